// Round 3
// baseline (2167.988 us; speedup 1.0000x reference)
//
#include <hip/hip_runtime.h>
#include <math.h>

#define D 128
#define MAXNORM 0.996f            // (1 - 4e-3)/sqrt(c), c = 1
#define MINNORM 1e-15f
#define ATCLAMP (1.0f - 1e-7f)

typedef unsigned int   u32;
typedef unsigned short u16;

__device__ __forceinline__ float wsum(float v) {
#pragma unroll
  for (int m = 32; m; m >>= 1) v += __shfl_xor(v, m);
  return v;
}

__device__ __forceinline__ float artanh_c(float x) {
  x = fminf(x, ATCLAMP);
  return 0.5f * logf((1.0f + x) / (1.0f - x));
}

__device__ __forceinline__ float bflo(u32 u) { return __uint_as_float(u << 16); }
__device__ __forceinline__ float bfhi(u32 u) { return __uint_as_float(u & 0xffff0000u); }
__device__ __forceinline__ u16 f2bf(float f) {            // RNE f32 -> bf16
  u32 u = __float_as_uint(f);
  return (u16)((u + 0x7fffu + ((u >> 16) & 1u)) >> 16);
}

// ---- runtime dtype detection (wave-uniform; call with all 64 lanes active) ----
// bf16-packed float buffer: low 16 bits of each dword are themselves a small bf16
// value (all inputs here have |v| < 1). f32 buffer: low halves are mantissa bits ->
// random exponent as bf16 -> some lane sees |v| >= 1 with P ~ 1 - 2^-64.
__device__ __forceinline__ bool detect_bf16(const u32* p) {
  float lo = fabsf(bflo(p[threadIdx.x & 63]));
  return (bool)__all(lo < 1.0f);
}
// int64 edge_index: values < 2^31 so every odd dword (high word) is 0.
__device__ __forceinline__ bool detect_i64(const int* p) {
  return (bool)__all(p[2 * (threadIdx.x & 63) + 1] == 0);
}

// ---------------- K0: zero the f32 accumulator ----------------
extern "C" __global__ __launch_bounds__(256) void k0_zero(float4* p, int n4) {
  int i = blockIdx.x * 256 + threadIdx.x;
  if (i < n4) p[i] = make_float4(0.f, 0.f, 0.f, 0.f);
}

// ---------------- K1: mobius_matvec + proj + mobius_add(bias) + proj + logmap0 ----
// One row per wave; lane j owns output cols j and j+64. W read from global (L1-hot).
template<bool BF>
__device__ __forceinline__ void k1_body(const void* xv, const void* Wv,
                                        const void* bv, void* xtv, int N) {
  __shared__ float xrow[4][D];
  const int lane = threadIdx.x & 63, wid = threadIdx.x >> 6;
  const int j = lane;

  // hyp_bias = proj(expmap0(bias)); lane holds cols j, j+64
  float bA, bB;
  if (BF) {
    const u16* b = (const u16*)bv;
    bA = __uint_as_float(((u32)b[j]) << 16);
    bB = __uint_as_float(((u32)b[j + 64]) << 16);
  } else {
    const float* b = (const float*)bv;
    bA = b[j]; bB = b[j + 64];
  }
  {
    float nb = fmaxf(sqrtf(wsum(bA * bA + bB * bB)), MINNORM);
    float s = tanhf(nb) / nb;
    float n1 = s * nb;
    if (n1 > MAXNORM) s *= MAXNORM / n1;
    bA *= s; bB *= s;
  }
  const float y2 = wsum(bA * bA + bB * bB);

  const int gw = blockIdx.x * 4 + wid;
  const int nw = gridDim.x * 4;
  const int iters = (N + nw - 1) / nw;   // uniform across block -> balanced syncthreads

  for (int it = 0; it < iters; ++it) {
    const int row = gw + it * nw;
    const int rowc = (row < N) ? row : (N - 1);
    // stage this wave's x row to f32 LDS + row norm
    float ss;
    if (BF) {
      u32 u = ((const u32*)xv)[(size_t)rowc * 64 + lane];
      float a = bflo(u), c = bfhi(u);
      xrow[wid][2 * lane] = a; xrow[wid][2 * lane + 1] = c;
      ss = a * a + c * c;
    } else {
      float a = ((const float*)xv)[(size_t)rowc * D + lane];
      float c = ((const float*)xv)[(size_t)rowc * D + 64 + lane];
      xrow[wid][lane] = a; xrow[wid][lane + 64] = c;
      ss = a * a + c * c;
    }
    const float xn = fmaxf(sqrtf(wsum(ss)), MINNORM);
    __syncthreads();

    float accA = 0.f, accB = 0.f;
    if (BF) {
      const u32* Ww = (const u32*)Wv;     // row j = 64 dwords at j*64
#pragma unroll 8
      for (int kk = 0; kk < 64; ++kk) {
        u32 wa = Ww[j * 64 + kk];
        u32 wb = Ww[(j + 64) * 64 + kk];
        float x0 = xrow[wid][2 * kk], x1 = xrow[wid][2 * kk + 1];
        accA += x0 * bflo(wa) + x1 * bfhi(wa);
        accB += x0 * bflo(wb) + x1 * bfhi(wb);
      }
    } else {
      const float* Wf = (const float*)Wv;
#pragma unroll 8
      for (int k = 0; k < D; ++k) {
        float xk = xrow[wid][k];
        accA += xk * Wf[j * D + k];
        accB += xk * Wf[(j + 64) * D + k];
      }
    }
    // hyperbolic epilogue
    float mxn = fmaxf(sqrtf(wsum(accA * accA + accB * accB)), MINNORM);
    float r = tanhf(mxn / xn * artanh_c(xn)) / mxn;     // mobius_matvec scale
    float mvA = r * accA, mvB = r * accB;
    float pn = r * mxn;
    if (pn > MAXNORM) { float sc = MAXNORM / pn; mvA *= sc; mvB *= sc; pn = MAXNORM; }
    float x2 = pn * pn;                                  // mobius_add with hyp_bias
    float xy = wsum(mvA * bA + mvB * bB);
    float ca = 1.f + 2.f * xy + y2;
    float cb = 1.f - x2;
    float den = fmaxf(1.f + 2.f * xy + x2 * y2, MINNORM);
    float hA = (ca * mvA + cb * bA) / den;
    float hB = (ca * mvB + cb * bB) / den;
    float hn = fmaxf(sqrtf(wsum(hA * hA + hB * hB)), MINNORM);  // proj + logmap0
    float ps = (hn > MAXNORM) ? (MAXNORM / hn) : 1.f;
    float np = fmaxf(hn * ps, MINNORM);
    float tsc = artanh_c(np) / np * ps;
    if (row < N) {
      if (BF) {
        u16* xt = (u16*)xtv;
        xt[(size_t)row * D + j]      = f2bf(tsc * hA);
        xt[(size_t)row * D + j + 64] = f2bf(tsc * hB);
      } else {
        float* xt = (float*)xtv;
        xt[(size_t)row * D + j]      = tsc * hA;
        xt[(size_t)row * D + j + 64] = tsc * hB;
      }
    }
    __syncthreads();
  }
}

extern "C" __global__ __launch_bounds__(256)
void OriginHyperbolicGraphConvolution_38628935860614_kernel(
    const void* x, const void* W, const void* b, void* xt, int N) {
  if (detect_bf16((const u32*)x)) k1_body<true>(x, W, b, xt, N);
  else                            k1_body<false>(x, W, b, xt, N);
}

// ---------------- K2: scatter-add  sup[dst] += w * xt[src]  (f32 atomics) ----------
extern "C" __global__ __launch_bounds__(256) void k2_spmm(
    const int* ei, const void* ew, const void* xt, float* sup, int E, int N) {
  const bool bf  = detect_bf16((const u32*)ew);   // before any early return
  const bool i64 = detect_i64(ei);
  const int lane = threadIdx.x & 63;
  const int e = blockIdx.x * 4 + (threadIdx.x >> 6);
  if (e >= E) return;
  int dst, src;
  if (i64) { dst = ei[2 * (size_t)e]; src = ei[2 * ((size_t)E + e)]; }
  else     { dst = ei[e];             src = ei[(size_t)E + e]; }
  if ((unsigned)dst >= (unsigned)N || (unsigned)src >= (unsigned)N) return;
  float w;
  if (bf) w = __uint_as_float(((u32)((const u16*)ew)[e]) << 16);
  else    w = ((const float*)ew)[e];
  float v0, v1;
  if (bf) {
    u32 u = ((const u32*)xt)[(size_t)src * 64 + lane];
    v0 = bflo(u); v1 = bfhi(u);
  } else {
    const float* xf = (const float*)xt;
    v0 = xf[(size_t)src * D + 2 * lane];
    v1 = xf[(size_t)src * D + 2 * lane + 1];
  }
  float* p = sup + (size_t)dst * D + 2 * lane;
  atomicAdd(p,     w * v0);
  atomicAdd(p + 1, w * v1);
}

// ---------------- K3: expmap0 -> proj -> logmap0 -> relu -> expmap0 -> proj --------
extern "C" __global__ __launch_bounds__(256) void k3_final(
    const float* sup, void* out, const void* xdet, int N) {
  const bool bf = detect_bf16((const u32*)xdet);
  const int lane = threadIdx.x & 63;
  const int row = blockIdx.x * 4 + (threadIdx.x >> 6);
  if (row >= N) return;
  float2 s = ((const float2*)sup)[(size_t)row * 64 + lane];
  float n = fmaxf(sqrtf(wsum(s.x * s.x + s.y * s.y)), MINNORM);
  float m  = tanhf(n) / n;                 // expmap0 scale
  float n1 = tanhf(n);
  if (n1 > MAXNORM) { m *= MAXNORM / n1; n1 = MAXNORM; }
  float nn = fmaxf(n1, MINNORM);           // logmap0
  m *= artanh_c(nn) / nn;
  float tA = fmaxf(m * s.x, 0.f), tB = fmaxf(m * s.y, 0.f);   // relu (m >= 0)
  float nr = fmaxf(sqrtf(wsum(tA * tA + tB * tB)), MINNORM);  // expmap0 + proj
  float m2 = tanhf(nr) / nr;
  float n2 = tanhf(nr);
  if (n2 > MAXNORM) m2 *= MAXNORM / n2;
  float oA = m2 * tA, oB = m2 * tB;
  if (bf) {
    u32 o = ((u32)f2bf(oA)) | (((u32)f2bf(oB)) << 16);
    ((u32*)out)[(size_t)row * 64 + lane] = o;
  } else {
    ((float2*)out)[(size_t)row * 64 + lane] = make_float2(oA, oB);
  }
}

extern "C" void kernel_launch(void* const* d_in, const int* in_sizes, int n_in,
                              void* d_out, int out_size, void* d_ws, size_t ws_size,
                              hipStream_t stream) {
  const void* x    = d_in[0];
  const void* W    = d_in[1];
  const void* bias = d_in[2];
  const int*  ei   = (const int*)d_in[3];
  const void* ew   = d_in[4];
  const int N = in_sizes[0] / D;
  const int E = in_sizes[4];

  float* sup = (float*)d_ws;               // f32 accumulator, N*D*4 = 51.2 MB
  void*  xt  = d_out;                      // tangent scratch (bf16 or f32), overwritten by K3

  const int n4 = (N * D) / 4;
  k0_zero<<<(n4 + 255) / 256, 256, 0, stream>>>((float4*)sup, n4);
  OriginHyperbolicGraphConvolution_38628935860614_kernel<<<512, 256, 0, stream>>>(
      x, W, bias, xt, N);
  k2_spmm<<<(E + 3) / 4, 256, 0, stream>>>(ei, ew, xt, sup, E, N);
  k3_final<<<(N + 3) / 4, 256, 0, stream>>>(sup, d_out, x, N);
}

// Round 4
// 729.551 us; speedup vs baseline: 2.9717x; 2.9717x over previous
//
#include <hip/hip_runtime.h>
#include <math.h>

#define D 128
#define WP 132                    // LDS W row stride (ushorts): 264 B rows, 8B-aligned
#define MAXNORM 0.996f            // (1 - 4e-3)/sqrt(c), c = 1
#define MINNORM 1e-15f
#define ATCLAMP (1.0f - 1e-7f)

typedef unsigned int   u32;
typedef unsigned short u16;

__device__ __forceinline__ float wsum(float v) {
#pragma unroll
  for (int m = 32; m; m >>= 1) v += __shfl_xor(v, m);
  return v;
}

__device__ __forceinline__ float artanh_c(float x) {
  x = fminf(x, ATCLAMP);
  return 0.5f * logf((1.0f + x) / (1.0f - x));
}

__device__ __forceinline__ float bflo(u32 u) { return __uint_as_float(u << 16); }
__device__ __forceinline__ float bfhi(u32 u) { return __uint_as_float(u & 0xffff0000u); }
__device__ __forceinline__ u16 f2bf(float f) {            // RNE f32 -> bf16
  u32 u = __float_as_uint(f);
  return (u16)((u + 0x7fffu + ((u >> 16) & 1u)) >> 16);
}

// ---- runtime dtype detection (wave-uniform; call before any divergence) ----
__device__ __forceinline__ bool detect_bf16(const u32* p) {
  float lo = fabsf(bflo(p[threadIdx.x & 63]));
  return (bool)__all(lo < 1.0f);
}
__device__ __forceinline__ bool detect_i64(const int* p) {
  return (bool)__all(p[2 * (threadIdx.x & 63) + 1] == 0);
}

// ---------------- K0: zero int buffer ----------------
extern "C" __global__ __launch_bounds__(256) void k0_zeroi(int* p, int n) {
  int i = blockIdx.x * 256 + threadIdx.x;
  if (i < n) p[i] = 0;
}

// ====== K1: mobius_matvec + proj + mobius_add(bias) + proj + logmap0 ======
// Block = 256 thr (4 waves) handles 16 rows; wave handles 4 rows; lane j owns
// output cols j, j+64. bf16 path: W staged in LDS; x rows staged f32 in LDS.
template<bool BF>
__device__ __forceinline__ void k1_body(const void* xv, const void* Wv,
                                        const void* bv, u16* xt, int N,
                                        u16* Wl, float (*xs)[D]) {
  const int tid  = threadIdx.x;
  const int lane = tid & 63;
  const int wid  = tid >> 6;
  const int jA = lane, jB = lane + 64;

  // hyp_bias = proj(expmap0(bias)); each wave computes redundantly
  float bA, bB;
  if (BF) {
    const u16* b = (const u16*)bv;
    bA = __uint_as_float(((u32)b[jA]) << 16);
    bB = __uint_as_float(((u32)b[jB]) << 16);
  } else {
    const float* b = (const float*)bv;
    bA = b[jA]; bB = b[jB];
  }
  {
    float nb = fmaxf(sqrtf(wsum(bA * bA + bB * bB)), MINNORM);
    float s = tanhf(nb) / nb;
    float n1 = s * nb;
    if (n1 > MAXNORM) s *= MAXNORM / n1;
    bA *= s; bB *= s;
  }
  const float y2 = wsum(bA * bA + bB * bB);

  // stage W into LDS (bf16 path only)
  if (BF) {
    const u32* Wu = (const u32*)Wv;          // 8192 dwords
    for (int dw = tid; dw < (D * D) / 2; dw += 256) {
      int row = dw >> 6, col = (dw & 63) * 2;
      *(u32*)&Wl[row * WP + col] = Wu[dw];
    }
  }

  // stage this block's 16 x rows as f32
  const int r0 = blockIdx.x * 16;
  if (BF) {
    const u32* xu = (const u32*)xv;
    for (int i = tid; i < 16 * 64; i += 256) {
      int rr = i >> 6, ln = i & 63;
      int row = r0 + rr;
      float a = 0.f, c = 0.f;
      if (row < N) { u32 u = xu[(size_t)row * 64 + ln]; a = bflo(u); c = bfhi(u); }
      xs[rr][2 * ln] = a; xs[rr][2 * ln + 1] = c;
    }
  } else {
    const float* xf = (const float*)xv;
    for (int i = tid; i < 16 * D; i += 256) {
      int rr = i >> 7, k = i & (D - 1);
      int row = r0 + rr;
      xs[rr][k] = (row < N) ? xf[(size_t)row * D + k] : 0.f;
    }
  }
  __syncthreads();

  // row norms for this wave's 4 rows
  float xn[4];
#pragma unroll
  for (int rr = 0; rr < 4; ++rr) {
    float a = xs[wid * 4 + rr][2 * lane], c = xs[wid * 4 + rr][2 * lane + 1];
    xn[rr] = fmaxf(sqrtf(wsum(a * a + c * c)), MINNORM);
  }

  // mx = W @ x, 4 rows x 2 cols per lane
  float accA[4] = {0.f, 0.f, 0.f, 0.f};
  float accB[4] = {0.f, 0.f, 0.f, 0.f};
  if (BF) {
#pragma unroll 4
    for (int kk = 0; kk < 32; ++kk) {
      uint2 wa = *(const uint2*)&Wl[jA * WP + 4 * kk];
      uint2 wb = *(const uint2*)&Wl[jB * WP + 4 * kk];
      float wa0 = bflo(wa.x), wa1 = bfhi(wa.x), wa2 = bflo(wa.y), wa3 = bfhi(wa.y);
      float wb0 = bflo(wb.x), wb1 = bfhi(wb.x), wb2 = bflo(wb.y), wb3 = bfhi(wb.y);
#pragma unroll
      for (int rr = 0; rr < 4; ++rr) {
        float4 xk = *(const float4*)&xs[wid * 4 + rr][4 * kk];   // uniform -> LDS broadcast
        accA[rr] += xk.x * wa0 + xk.y * wa1 + xk.z * wa2 + xk.w * wa3;
        accB[rr] += xk.x * wb0 + xk.y * wb1 + xk.z * wb2 + xk.w * wb3;
      }
    }
  } else {
    const float* Wf = (const float*)Wv;
#pragma unroll 4
    for (int k = 0; k < D; ++k) {
      float wka = Wf[jA * D + k], wkb = Wf[jB * D + k];
#pragma unroll
      for (int rr = 0; rr < 4; ++rr) {
        float xk = xs[wid * 4 + rr][k];
        accA[rr] += xk * wka;
        accB[rr] += xk * wkb;
      }
    }
  }

  // hyperbolic epilogue per row; xt output is ALWAYS bf16 (internal format)
#pragma unroll
  for (int rr = 0; rr < 4; ++rr) {
    int row = r0 + wid * 4 + rr;
    float mxn = fmaxf(sqrtf(wsum(accA[rr] * accA[rr] + accB[rr] * accB[rr])), MINNORM);
    float r = tanhf(mxn / xn[rr] * artanh_c(xn[rr])) / mxn;     // mobius_matvec scale
    float mvA = r * accA[rr], mvB = r * accB[rr];
    float pn = r * mxn;
    if (pn > MAXNORM) { float sc = MAXNORM / pn; mvA *= sc; mvB *= sc; pn = MAXNORM; }
    float x2 = pn * pn;                                          // mobius_add(mv, hyp_bias)
    float xy = wsum(mvA * bA + mvB * bB);
    float ca = 1.f + 2.f * xy + y2;
    float cb = 1.f - x2;
    float den = fmaxf(1.f + 2.f * xy + x2 * y2, MINNORM);
    float hA = (ca * mvA + cb * bA) / den;
    float hB = (ca * mvB + cb * bB) / den;
    float hn = fmaxf(sqrtf(wsum(hA * hA + hB * hB)), MINNORM);   // proj + logmap0
    float ps = (hn > MAXNORM) ? (MAXNORM / hn) : 1.f;
    float np = fmaxf(hn * ps, MINNORM);
    float tsc = artanh_c(np) / np * ps;
    if (row < N) {
      xt[(size_t)row * D + jA] = f2bf(tsc * hA);
      xt[(size_t)row * D + jB] = f2bf(tsc * hB);
    }
  }
}

extern "C" __global__ __launch_bounds__(256)
void OriginHyperbolicGraphConvolution_38628935860614_kernel(
    const void* x, const void* W, const void* b, u16* xt, int N) {
  __shared__ u16 Wl[D * WP];            // 33.8 KB
  __shared__ __align__(16) float xs[16][D];  // 8 KB
  if (detect_bf16((const u32*)x)) k1_body<true >(x, W, b, xt, N, Wl, xs);
  else                            k1_body<false>(x, W, b, xt, N, Wl, xs);
}

// ====== K2a: histogram of dst ======
extern "C" __global__ __launch_bounds__(256) void khist(
    const int* ei, int* bins, int E, int N) {
  const bool i64 = detect_i64(ei);
  int e = blockIdx.x * 256 + threadIdx.x;
  if (e >= E) return;
  int dst, src;
  if (i64) { dst = ei[2 * (size_t)e]; src = ei[2 * ((size_t)E + e)]; }
  else     { dst = ei[e];             src = ei[(size_t)E + e]; }
  if ((unsigned)dst < (unsigned)N && (unsigned)src < (unsigned)N)
    atomicAdd(&bins[dst], 1);
}

// ====== K2b/c/d: exclusive scan of bins -> offsets (3-kernel scan) ======
extern "C" __global__ __launch_bounds__(256) void kscan1(
    const int* bins, int* offs, int* part, int N) {
  __shared__ int sc[256];
  const int tid = threadIdx.x;
  const int i = blockIdx.x * 256 + tid;
  int v = (i < N) ? bins[i] : 0;
  sc[tid] = v; __syncthreads();
#pragma unroll
  for (int off = 1; off < 256; off <<= 1) {
    int t = (tid >= off) ? sc[tid - off] : 0;
    __syncthreads();
    sc[tid] += t;
    __syncthreads();
  }
  if (i <= N) offs[i] = sc[tid] - v;        // local exclusive
  if (tid == 255) part[blockIdx.x] = sc[255];
}

extern "C" __global__ __launch_bounds__(1024) void kscan2(
    int* part, int* offs, int B, int N) {
  __shared__ int sc[1024];
  const int tid = threadIdx.x;
  int v = (tid < B) ? part[tid] : 0;
  sc[tid] = v; __syncthreads();
#pragma unroll
  for (int off = 1; off < 1024; off <<= 1) {
    int t = (tid >= off) ? sc[tid - off] : 0;
    __syncthreads();
    sc[tid] += t;
    __syncthreads();
  }
  if (tid < B) part[tid] = sc[tid] - v;     // exclusive block bases
  if (tid == 1023) offs[N] = sc[1023];      // total = E_valid
}

extern "C" __global__ __launch_bounds__(256) void kscan3(
    int* offs, int* cursor, const int* part, int N) {
  const int i = blockIdx.x * 256 + threadIdx.x;
  if (i < N) {
    int o = offs[i] + part[blockIdx.x];
    offs[i] = o;
    cursor[i] = o;
  }
}

// ====== K2e: scatter edges into dst-sorted order ======
extern "C" __global__ __launch_bounds__(256) void kscatter(
    const int* ei, const void* ew, int* cursor,
    int* ssrc, float* sw, int E, int N) {
  const bool bf  = detect_bf16((const u32*)ew);
  const bool i64 = detect_i64(ei);
  int e = blockIdx.x * 256 + threadIdx.x;
  if (e >= E) return;
  int dst, src;
  if (i64) { dst = ei[2 * (size_t)e]; src = ei[2 * ((size_t)E + e)]; }
  else     { dst = ei[e];             src = ei[(size_t)E + e]; }
  if ((unsigned)dst >= (unsigned)N || (unsigned)src >= (unsigned)N) return;
  float w;
  if (bf) w = __uint_as_float(((u32)((const u16*)ew)[e]) << 16);
  else    w = ((const float*)ew)[e];
  int pos = atomicAdd(&cursor[dst], 1);
  ssrc[pos] = src;
  sw[pos]   = w;
}

// ====== K3: gather-aggregate per node + fused finalize ======
// wave per node: sup = sum_e w_e * xt[src_e]; then expmap0->proj->logmap0->relu->expmap0->proj
extern "C" __global__ __launch_bounds__(256) void kagg(
    const int* offs, const int* ssrc, const float* sw, const u16* xt,
    void* out, const void* xdet, int N) {
  const bool bf = detect_bf16((const u32*)xdet);
  const int lane = threadIdx.x & 63;
  const int node = blockIdx.x * 4 + (threadIdx.x >> 6);
  if (node >= N) return;
  const int s0 = offs[node], s1 = offs[node + 1];
  const u32* xtw = (const u32*)xt;
  float a0 = 0.f, a1 = 0.f;
  for (int e = s0; e < s1; ++e) {
    const int s = ssrc[e];                  // uniform -> scalar load
    const float w = sw[e];
    u32 u = xtw[(size_t)s * 64 + lane];     // coalesced 256 B row gather
    a0 += w * bflo(u);
    a1 += w * bfhi(u);
  }
  // finalize (round-3 K3 math, verified)
  float n = fmaxf(sqrtf(wsum(a0 * a0 + a1 * a1)), MINNORM);
  float m  = tanhf(n) / n;                  // expmap0 scale
  float n1 = tanhf(n);
  if (n1 > MAXNORM) { m *= MAXNORM / n1; n1 = MAXNORM; }
  float nn = fmaxf(n1, MINNORM);            // logmap0
  m *= artanh_c(nn) / nn;
  float tA = fmaxf(m * a0, 0.f), tB = fmaxf(m * a1, 0.f);     // relu (m >= 0)
  float nr = fmaxf(sqrtf(wsum(tA * tA + tB * tB)), MINNORM);  // expmap0 + proj
  float m2 = tanhf(nr) / nr;
  float n2 = tanhf(nr);
  if (n2 > MAXNORM) m2 *= MAXNORM / n2;
  float oA = m2 * tA, oB = m2 * tB;
  if (bf) {
    u32 o = ((u32)f2bf(oA)) | (((u32)f2bf(oB)) << 16);
    ((u32*)out)[(size_t)node * 64 + lane] = o;
  } else {
    ((float2*)out)[(size_t)node * 64 + lane] = make_float2(oA, oB);
  }
}

extern "C" void kernel_launch(void* const* d_in, const int* in_sizes, int n_in,
                              void* d_out, int out_size, void* d_ws, size_t ws_size,
                              hipStream_t stream) {
  const void* x    = d_in[0];
  const void* W    = d_in[1];
  const void* bias = d_in[2];
  const int*  ei   = (const int*)d_in[3];
  const void* ew   = d_in[4];
  const int N = in_sizes[0] / D;
  const int E = in_sizes[4];

  // workspace layout (256-B aligned chunks)
  char* ws = (char*)d_ws;
  size_t off = 0;
  auto carve = [&](size_t bytes) { char* p = ws + off; off = (off + bytes + 255) & ~(size_t)255; return p; };
  u16*   xt     = (u16*)  carve((size_t)N * D * sizeof(u16));   // 25.6 MB
  int*   ssrc   = (int*)  carve((size_t)E * sizeof(int));       //  6.4 MB
  float* sw     = (float*)carve((size_t)E * sizeof(float));     //  6.4 MB
  int*   offs   = (int*)  carve((size_t)(N + 1) * sizeof(int));
  int*   cursor = (int*)  carve((size_t)N * sizeof(int));
  int*   bins   = (int*)  carve((size_t)N * sizeof(int));
  int*   part   = (int*)  carve(1024 * sizeof(int));

  const int B = (N + 255) / 256;   // scan blocks (N=100k -> 391 <= 1024)

  k0_zeroi<<<B, 256, 0, stream>>>(bins, N);
  OriginHyperbolicGraphConvolution_38628935860614_kernel<<<(N + 15) / 16, 256, 0, stream>>>(
      x, W, bias, xt, N);
  khist   <<<(E + 255) / 256, 256, 0, stream>>>(ei, bins, E, N);
  kscan1  <<<B, 256, 0, stream>>>(bins, offs, part, N);
  kscan2  <<<1, 1024, 0, stream>>>(part, offs, B, N);
  kscan3  <<<B, 256, 0, stream>>>(offs, cursor, part, N);
  kscatter<<<(E + 255) / 256, 256, 0, stream>>>(ei, ew, cursor, ssrc, sw, E, N);
  kagg    <<<(N + 3) / 4, 256, 0, stream>>>(offs, ssrc, sw, xt, d_out, x, N);
}

// Round 5
// 696.690 us; speedup vs baseline: 3.1118x; 1.0472x over previous
//
#include <hip/hip_runtime.h>
#include <math.h>

#define D 128
#define WP 132                    // LDS W row stride (ushorts): 264 B rows, 8B-aligned
#define MAXNORM 0.996f            // (1 - 4e-3)/sqrt(c), c = 1
#define MINNORM 1e-15f
#define ATCLAMP (1.0f - 1e-7f)

typedef unsigned int   u32;
typedef unsigned short u16;

__device__ __forceinline__ float wsum(float v) {
#pragma unroll
  for (int m = 32; m; m >>= 1) v += __shfl_xor(v, m);
  return v;
}

__device__ __forceinline__ float frcp(float x) { return __builtin_amdgcn_rcpf(x); }

// fast artanh for x in [0, 1-1e-7]
__device__ __forceinline__ float fast_artanh(float x) {
  x = fminf(x, ATCLAMP);
  return 0.5f * __logf((1.0f + x) * frcp(1.0f - x));
}
// fast tanh for z >= 0
__device__ __forceinline__ float fast_tanh(float z) {
  float t = __expf(-2.0f * z);
  return (1.0f - t) * frcp(1.0f + t);
}

__device__ __forceinline__ float bflo(u32 u) { return __uint_as_float(u << 16); }
__device__ __forceinline__ float bfhi(u32 u) { return __uint_as_float(u & 0xffff0000u); }
__device__ __forceinline__ u16 f2bf(float f) {            // RNE f32 -> bf16
  u32 u = __float_as_uint(f);
  return (u16)((u + 0x7fffu + ((u >> 16) & 1u)) >> 16);
}

// ---- runtime dtype detection (wave-uniform; call before any divergence) ----
__device__ __forceinline__ bool detect_bf16(const u32* p) {
  float lo = fabsf(bflo(p[threadIdx.x & 63]));
  return (bool)__all(lo < 1.0f);
}
__device__ __forceinline__ bool detect_i64(const int* p) {
  return (bool)__all(p[2 * (threadIdx.x & 63) + 1] == 0);
}

// ---------------- K0: zero int buffer ----------------
extern "C" __global__ __launch_bounds__(256) void k0_zeroi(int* p, int n) {
  int i = blockIdx.x * 256 + threadIdx.x;
  if (i < n) p[i] = 0;
}

// ====== K1: mobius_matvec + proj + mobius_add(bias) + proj + logmap0 ======
// Persistent blocks: W staged in LDS once; grid-stride over 4-row groups per wave.
// x rows read via wave-uniform scalar loads; lane j owns output cols j, j+64.
template<bool BF>
__device__ __forceinline__ void k1_body(const void* xv, const void* Wv,
                                        const void* bv, u16* xt, int N, u16* Wl) {
  const int tid  = threadIdx.x;
  const int lane = tid & 63;
  const int wid  = tid >> 6;
  const int jA = lane, jB = lane + 64;

  // hyp_bias = proj(expmap0(bias)); redundantly per wave
  float bA, bB;
  if (BF) {
    const u16* b = (const u16*)bv;
    bA = __uint_as_float(((u32)b[jA]) << 16);
    bB = __uint_as_float(((u32)b[jB]) << 16);
  } else {
    const float* b = (const float*)bv;
    bA = b[jA]; bB = b[jB];
  }
  {
    float nb = fmaxf(sqrtf(wsum(bA * bA + bB * bB)), MINNORM);
    float s = fast_tanh(nb) * frcp(nb);
    float n1 = s * nb;
    if (n1 > MAXNORM) s *= MAXNORM * frcp(n1);
    bA *= s; bB *= s;
  }
  const float y2 = wsum(bA * bA + bB * bB);
  const bool bias_zero = (y2 == 0.0f);      // wave-uniform

  // stage W once (bf16 path only)
  if (BF) {
    const uint2* Wu = (const uint2*)Wv;      // 4096 uint2 = 8 bf16-pairs
    for (int q = tid; q < (D * D) / 4; q += 256) {
      int row = q >> 5, col = (q & 31) * 4;  // 32 uint2 per row of 128
      *(uint2*)&Wl[row * WP + col] = Wu[q];  // 264*row + 8*col/4 -> 8B aligned
    }
    __syncthreads();
  }

  const int ngroups = (N + 3) / 4;
  const int nw = gridDim.x * 4;

  for (int g = blockIdx.x * 4 + wid; g < ngroups; g += nw) {
    const int r0 = g * 4;
    // row norms via coalesced vector load (x read again as scalars below; L2-hot)
    float xn[4];
    const uint2* xr[4];
#pragma unroll
    for (int rr = 0; rr < 4; ++rr) {
      int rowc = r0 + rr; if (rowc >= N) rowc = N - 1;
      rowc = __builtin_amdgcn_readfirstlane(rowc);
      if (BF) {
        xr[rr] = (const uint2*)xv + (size_t)rowc * 32;   // 32 uint2 per row
        u32 u = ((const u32*)xv)[(size_t)rowc * 64 + lane];
        float a = bflo(u), c = bfhi(u);
        xn[rr] = fmaxf(sqrtf(wsum(a * a + c * c)), MINNORM);
      } else {
        xr[rr] = (const uint2*)xv + (size_t)rowc * 64;   // 64 uint2 per row (f32)
        float a = ((const float*)xv)[(size_t)rowc * D + lane];
        float c = ((const float*)xv)[(size_t)rowc * D + 64 + lane];
        xn[rr] = fmaxf(sqrtf(wsum(a * a + c * c)), MINNORM);
      }
    }

    float accA[4] = {0.f, 0.f, 0.f, 0.f};
    float accB[4] = {0.f, 0.f, 0.f, 0.f};
    if (BF) {
#pragma unroll 4
      for (int kk = 0; kk < 32; ++kk) {      // 4 k-values per iter
        uint2 wa = *(const uint2*)&Wl[jA * WP + 4 * kk];
        uint2 wb = *(const uint2*)&Wl[jB * WP + 4 * kk];
        float wa0 = bflo(wa.x), wa1 = bfhi(wa.x), wa2 = bflo(wa.y), wa3 = bfhi(wa.y);
        float wb0 = bflo(wb.x), wb1 = bfhi(wb.x), wb2 = bflo(wb.y), wb3 = bfhi(wb.y);
#pragma unroll
        for (int rr = 0; rr < 4; ++rr) {
          uint2 xu = xr[rr][kk];             // wave-uniform -> scalar load
          float x0 = bflo(xu.x), x1 = bfhi(xu.x), x2 = bflo(xu.y), x3 = bfhi(xu.y);
          accA[rr] += x0 * wa0 + x1 * wa1 + x2 * wa2 + x3 * wa3;
          accB[rr] += x0 * wb0 + x1 * wb1 + x2 * wb2 + x3 * wb3;
        }
      }
    } else {
      const float* Wf = (const float*)Wv;
#pragma unroll 2
      for (int kk = 0; kk < 64; ++kk) {      // 2 k-values per iter
        float wa0 = Wf[jA * D + 2 * kk], wa1 = Wf[jA * D + 2 * kk + 1];
        float wb0 = Wf[jB * D + 2 * kk], wb1 = Wf[jB * D + 2 * kk + 1];
#pragma unroll
        for (int rr = 0; rr < 4; ++rr) {
          uint2 xu = xr[rr][kk];
          float x0 = __uint_as_float(xu.x), x1 = __uint_as_float(xu.y);
          accA[rr] += x0 * wa0 + x1 * wa1;
          accB[rr] += x0 * wb0 + x1 * wb1;
        }
      }
    }

    // hyperbolic epilogue; xt output always bf16 (internal format)
#pragma unroll
    for (int rr = 0; rr < 4; ++rr) {
      int row = r0 + rr;
      float mxn = fmaxf(sqrtf(wsum(accA[rr] * accA[rr] + accB[rr] * accB[rr])), MINNORM);
      float r = fast_tanh(mxn * frcp(xn[rr]) * fast_artanh(xn[rr])) * frcp(mxn);
      float mvA = r * accA[rr], mvB = r * accB[rr];
      float pn = r * mxn;
      if (pn > MAXNORM) { float sc = MAXNORM * frcp(pn); mvA *= sc; mvB *= sc; pn = MAXNORM; }
      float hA, hB, hn;
      if (bias_zero) {                       // mobius_add(mv, 0) == mv exactly
        hA = mvA; hB = mvB; hn = pn;
      } else {
        float x2 = pn * pn;
        float xy = wsum(mvA * bA + mvB * bB);
        float ca = 1.f + 2.f * xy + y2;
        float cb = 1.f - x2;
        float den = fmaxf(1.f + 2.f * xy + x2 * y2, MINNORM);
        float id = frcp(den);
        hA = (ca * mvA + cb * bA) * id;
        hB = (ca * mvB + cb * bB) * id;
        hn = fmaxf(sqrtf(wsum(hA * hA + hB * hB)), MINNORM);
      }
      float ps = (hn > MAXNORM) ? (MAXNORM * frcp(hn)) : 1.f;   // proj
      float np = fmaxf(hn * ps, MINNORM);                        // + logmap0
      float tsc = fast_artanh(np) * frcp(np) * ps;
      if (row < N) {
        xt[(size_t)row * D + jA] = f2bf(tsc * hA);
        xt[(size_t)row * D + jB] = f2bf(tsc * hB);
      }
    }
  }
}

extern "C" __global__ __launch_bounds__(256)
void OriginHyperbolicGraphConvolution_38628935860614_kernel(
    const void* x, const void* W, const void* b, u16* xt, int N) {
  __shared__ u16 Wl[D * WP];                 // 33.8 KB -> 4 blocks/CU
  if (detect_bf16((const u32*)x)) k1_body<true >(x, W, b, xt, N, Wl);
  else                            k1_body<false>(x, W, b, xt, N, Wl);
}

// ====== K2a: histogram of dst ======
extern "C" __global__ __launch_bounds__(256) void khist(
    const int* ei, int* bins, int E, int N) {
  const bool i64 = detect_i64(ei);
  int e = blockIdx.x * 256 + threadIdx.x;
  if (e >= E) return;
  int dst, src;
  if (i64) { dst = ei[2 * (size_t)e]; src = ei[2 * ((size_t)E + e)]; }
  else     { dst = ei[e];             src = ei[(size_t)E + e]; }
  if ((unsigned)dst < (unsigned)N && (unsigned)src < (unsigned)N)
    atomicAdd(&bins[dst], 1);
}

// ====== K2b/c/d: exclusive scan of bins -> offsets ======
extern "C" __global__ __launch_bounds__(256) void kscan1(
    const int* bins, int* offs, int* part, int N) {
  __shared__ int sc[256];
  const int tid = threadIdx.x;
  const int i = blockIdx.x * 256 + tid;
  int v = (i < N) ? bins[i] : 0;
  sc[tid] = v; __syncthreads();
#pragma unroll
  for (int off = 1; off < 256; off <<= 1) {
    int t = (tid >= off) ? sc[tid - off] : 0;
    __syncthreads();
    sc[tid] += t;
    __syncthreads();
  }
  if (i <= N) offs[i] = sc[tid] - v;
  if (tid == 255) part[blockIdx.x] = sc[255];
}

extern "C" __global__ __launch_bounds__(1024) void kscan2(
    int* part, int* offs, int B, int N) {
  __shared__ int sc[1024];
  const int tid = threadIdx.x;
  int v = (tid < B) ? part[tid] : 0;
  sc[tid] = v; __syncthreads();
#pragma unroll
  for (int off = 1; off < 1024; off <<= 1) {
    int t = (tid >= off) ? sc[tid - off] : 0;
    __syncthreads();
    sc[tid] += t;
    __syncthreads();
  }
  if (tid < B) part[tid] = sc[tid] - v;
  if (tid == 1023) offs[N] = sc[1023];
}

extern "C" __global__ __launch_bounds__(256) void kscan3(
    int* offs, int* cursor, const int* part, int N) {
  const int i = blockIdx.x * 256 + threadIdx.x;
  if (i < N) {
    int o = offs[i] + part[blockIdx.x];
    offs[i] = o;
    cursor[i] = o;
  }
}

// ====== K2e: scatter edges into dst-sorted order, packed (src, w_bits) ======
extern "C" __global__ __launch_bounds__(256) void kscatter(
    const int* ei, const void* ew, int* cursor, uint2* esrt, int E, int N) {
  const bool bf  = detect_bf16((const u32*)ew);
  const bool i64 = detect_i64(ei);
  int e = blockIdx.x * 256 + threadIdx.x;
  if (e >= E) return;
  int dst, src;
  if (i64) { dst = ei[2 * (size_t)e]; src = ei[2 * ((size_t)E + e)]; }
  else     { dst = ei[e];             src = ei[(size_t)E + e]; }
  if ((unsigned)dst >= (unsigned)N || (unsigned)src >= (unsigned)N) return;
  float w;
  if (bf) w = __uint_as_float(((u32)((const u16*)ew)[e]) << 16);
  else    w = ((const float*)ew)[e];
  int pos = atomicAdd(&cursor[dst], 1);
  esrt[pos] = make_uint2((u32)src, __float_as_uint(w));
}

// ====== K3: gather-aggregate per node + fused finalize ======
extern "C" __global__ __launch_bounds__(256) void kagg(
    const int* offs, const uint2* esrt, const u16* xt,
    void* out, const void* xdet, int N) {
  const bool bf = detect_bf16((const u32*)xdet);
  const int lane = threadIdx.x & 63;
  const int node = blockIdx.x * 4 + (threadIdx.x >> 6);
  if (node >= N) return;
  const int s0 = offs[node], s1 = offs[node + 1];
  const u32* xtw = (const u32*)xt;
  float a0 = 0.f, a1 = 0.f;
  int e = s0;
  for (; e + 2 <= s1; e += 2) {              // 2 gathers in flight
    uint2 p0 = esrt[e], p1 = esrt[e + 1];    // uniform -> scalar loads
    u32 u0 = xtw[(size_t)p0.x * 64 + lane];
    u32 u1 = xtw[(size_t)p1.x * 64 + lane];
    float w0 = __uint_as_float(p0.y), w1 = __uint_as_float(p1.y);
    a0 += w0 * bflo(u0) + w1 * bflo(u1);
    a1 += w0 * bfhi(u0) + w1 * bfhi(u1);
  }
  if (e < s1) {
    uint2 p = esrt[e];
    u32 u = xtw[(size_t)p.x * 64 + lane];
    float w = __uint_as_float(p.y);
    a0 += w * bflo(u);
    a1 += w * bfhi(u);
  }
  // finalize: expmap0 -> proj -> logmap0 -> relu -> expmap0 -> proj
  float n = fmaxf(sqrtf(wsum(a0 * a0 + a1 * a1)), MINNORM);
  float tn = fast_tanh(n);
  float m = tn * frcp(n);
  if (tn > MAXNORM) { m *= MAXNORM * frcp(tn); tn = MAXNORM; }
  float nn = fmaxf(tn, MINNORM);
  m *= fast_artanh(nn) * frcp(nn);
  float tA = fmaxf(m * a0, 0.f), tB = fmaxf(m * a1, 0.f);      // relu (m >= 0)
  float nr = fmaxf(sqrtf(wsum(tA * tA + tB * tB)), MINNORM);
  float t2 = fast_tanh(nr);
  float m2 = t2 * frcp(nr);
  if (t2 > MAXNORM) m2 *= MAXNORM * frcp(t2);
  float oA = m2 * tA, oB = m2 * tB;
  if (bf) {
    u32 o = ((u32)f2bf(oA)) | (((u32)f2bf(oB)) << 16);
    ((u32*)out)[(size_t)node * 64 + lane] = o;
  } else {
    ((float2*)out)[(size_t)node * 64 + lane] = make_float2(oA, oB);
  }
}

extern "C" void kernel_launch(void* const* d_in, const int* in_sizes, int n_in,
                              void* d_out, int out_size, void* d_ws, size_t ws_size,
                              hipStream_t stream) {
  const void* x    = d_in[0];
  const void* W    = d_in[1];
  const void* bias = d_in[2];
  const int*  ei   = (const int*)d_in[3];
  const void* ew   = d_in[4];
  const int N = in_sizes[0] / D;
  const int E = in_sizes[4];

  char* ws = (char*)d_ws;
  size_t off = 0;
  auto carve = [&](size_t bytes) { char* p = ws + off; off = (off + bytes + 255) & ~(size_t)255; return p; };
  u16*   xt     = (u16*)  carve((size_t)N * D * sizeof(u16));    // 25.6 MB
  uint2* esrt   = (uint2*)carve((size_t)E * sizeof(uint2));      // 12.8 MB
  int*   offs   = (int*)  carve((size_t)(N + 1) * sizeof(int));
  int*   cursor = (int*)  carve((size_t)N * sizeof(int));
  int*   bins   = (int*)  carve((size_t)N * sizeof(int));
  int*   part   = (int*)  carve(1024 * sizeof(int));

  const int B = (N + 255) / 256;

  k0_zeroi<<<B, 256, 0, stream>>>(bins, N);
  OriginHyperbolicGraphConvolution_38628935860614_kernel<<<1024, 256, 0, stream>>>(
      x, W, bias, xt, N);
  khist   <<<(E + 255) / 256, 256, 0, stream>>>(ei, bins, E, N);
  kscan1  <<<B, 256, 0, stream>>>(bins, offs, part, N);
  kscan2  <<<1, 1024, 0, stream>>>(part, offs, B, N);
  kscan3  <<<B, 256, 0, stream>>>(offs, cursor, part, N);
  kscatter<<<(E + 255) / 256, 256, 0, stream>>>(ei, ew, cursor, esrt, E, N);
  kagg    <<<(N + 3) / 4, 256, 0, stream>>>(offs, esrt, xt, d_out, x, N);
}